// Round 7
// baseline (584.503 us; speedup 1.0000x reference)
//
#include <hip/hip_runtime.h>
#include <cstdint>

#define NCOLS   696    // 16+120+560 subsets of size<=3, bitmask order
#define NPAD    704
#define CHUNK   16     // columns per LDS staging chunk
#define NCHUNK  44     // 44*16 = 704
#define HALFCH  22     // chunks per block (2 blocks per 64-row group)
#define BLOCK   64     // one wave per block, lane = row
#define ROWS    64

typedef float v4f __attribute__((ext_vector_type(4)));

// Per-column descriptor: b0 | b1<<4 | triple<<8.
//   tmp = sel(iv[b1], iv[b0]);  res = triple ? sel(cur, tmp) : tmp;
//   cur <- tmp unless triple.
// single {h}:  (h,h)   tmp = sel(I_h,I_h) = I_h
// pair {j,h}:  (j,h)   tmp = sel(I_h,I_j) = reference pairres(j,h); becomes cur
// triple {i,j,h}: (i,j)+flag  tmp = pairres(i,j); res = sel(pair{j,h}=cur, tmp)
// Bitmask order guarantees pair{j,h} is emitted immediately before its triples,
// and singles harmlessly refresh cur. Validated semantics (absmax=0, rounds 1-6).
struct alignas(16) Desc { uint32_t d[NPAD]; };
constexpr Desc make_desc() {
    Desc t{};
    int p = 0;
    for (int h = 0; h < 16; ++h) {
        t.d[p++] = (uint32_t)(h | (h << 4));
        for (int j = 0; j < h; ++j) {
            t.d[p++] = (uint32_t)(j | (h << 4));
            for (int i = 0; i < j; ++i)
                t.d[p++] = (uint32_t)(i | (j << 4) | (1u << 8));
        }
    }
    for (; p < NPAD; ++p) t.d[p] = 0;   // pads: computed, never stored
    return t;
}
__constant__ Desc g_desc = make_desc();

// Tie-exact compare: s = RN(l+u) is the 0.5-scaled sum proxy (exact p2 scale),
// b = RN(RN(0.2l)+RN(0.8u)). Both are pure functions of (l,u), so propagating
// them through selects is bit-identical to recomputing (records are always
// copies of original intervals).
struct Rec { float l, u, s, b; };

__device__ __forceinline__ Rec mkrec(float2 I) {
    Rec r;
    r.l = I.x; r.u = I.y;
    r.s = __fadd_rn(I.x, I.y);
    r.b = __fadd_rn(__fmul_rn(0.2f, I.x), __fmul_rn(0.8f, I.y));
    return r;
}
__device__ __forceinline__ Rec selrec(Rec L, Rec R) {
    bool cr = (L.s == R.s) ? (L.b > R.b) : (L.s > R.s);
    return cr ? R : L;
}

__global__ __launch_bounds__(BLOCK) void minint_kernel(
    const float* __restrict__ xl, const float* __restrict__ xu,
    float* __restrict__ out, int batch)
{
    __shared__ float2 iv[16 * 64];     // iv[i*64+r]: transposed intervals (8 KB)
    __shared__ float2 st[CHUNK * 64];  // swizzled staging tile (8 KB)
    const int r    = threadIdx.x;
    const int grp  = blockIdx.x >> 1;          // 64-row group
    const int half = blockIdx.x & 1;           // column half: chunks [22h,22h+22)
    const size_t row = (size_t)grp * ROWS + r;

    // Load this lane's row and scatter transposed into LDS (same-wave
    // produce->consume; in-order DS pipe, no barrier; banks 2r: conflict-free).
    const float4* pl = (const float4*)(xl + row * 16);
    const float4* pu = (const float4*)(xu + row * 16);
    float4 a0 = pl[0], a1 = pl[1], a2 = pl[2], a3 = pl[3];
    float4 b0 = pu[0], b1 = pu[1], b2 = pu[2], b3 = pu[3];
    iv[ 0*64 + r] = make_float2(a0.x, b0.x);
    iv[ 1*64 + r] = make_float2(a0.y, b0.y);
    iv[ 2*64 + r] = make_float2(a0.z, b0.z);
    iv[ 3*64 + r] = make_float2(a0.w, b0.w);
    iv[ 4*64 + r] = make_float2(a1.x, b1.x);
    iv[ 5*64 + r] = make_float2(a1.y, b1.y);
    iv[ 6*64 + r] = make_float2(a1.z, b1.z);
    iv[ 7*64 + r] = make_float2(a1.w, b1.w);
    iv[ 8*64 + r] = make_float2(a2.x, b2.x);
    iv[ 9*64 + r] = make_float2(a2.y, b2.y);
    iv[10*64 + r] = make_float2(a2.z, b2.z);
    iv[11*64 + r] = make_float2(a2.w, b2.w);
    iv[12*64 + r] = make_float2(a3.x, b3.x);
    iv[13*64 + r] = make_float2(a3.y, b3.y);
    iv[14*64 + r] = make_float2(a3.z, b3.z);
    iv[15*64 + r] = make_float2(a3.w, b3.w);

    // Seed cur: half 0 starts at col 0 (single {0}, refreshes cur itself);
    // half 1 starts at col 352 = {7,9,12}, whose live pair is {9,12}.
    Rec cur;
    {
        int sj = half ? 9 : 0, sh = half ? 12 : 0;
        cur = selrec(mkrec(iv[sh * 64 + r]), mkrec(iv[sj * 64 + r]));
    }

    const size_t row0 = (size_t)grp * ROWS;
    float* outl = out + row0 * NCOLS;
    float* outu = out + (size_t)batch * NCOLS + row0 * NCOLS;

    for (int ch = 0; ch < HALFCH; ++ch) {
        const int gc = half * HALFCH + ch;     // global chunk
        const int C  = gc * CHUNK;
        // Compute 16 columns into the swizzled tile (banks 2(r+c): no conflict).
        #pragma unroll
        for (int c = 0; c < CHUNK; ++c) {
            uint32_t d = g_desc.d[C + c];                 // wave-uniform scalar
            Rec A = mkrec(iv[((d >> 4) & 15u) * 64 + r]); // L operand
            Rec B = mkrec(iv[(d & 15u) * 64 + r]);        // R operand
            Rec tmp = selrec(A, B);
            Rec two = selrec(cur, tmp);
            bool trip = (d >> 8) & 1u;
            float2 res = trip ? make_float2(two.l, two.u)
                              : make_float2(tmp.l, tmp.u);
            if (!trip) cur = tmp;                          // branchless cndmask
            st[c * 64 + ((r + c) & 63)] = res;
        }
        // Flush: lane -> (rows rr = r>>2 + 16q, col-quad cq = r&3).
        // 4 ascending lanes = 64B contiguous per row; no write amplification
        // observed with this family of patterns (round 6 WRITE_SIZE == ideal).
        const int ncq = (gc == NCHUNK - 1) ? 2 : 4;        // last chunk: 8 real cols
        const int cq = r & 3;
        #pragma unroll
        for (int q = 0; q < 4; ++q) {
            const int rr = (r >> 2) + q * 16;
            if (cq < ncq) {
                const int c0 = cq * 4;
                float2 e0 = st[(c0 + 0) * 64 + ((rr + c0 + 0) & 63)];
                float2 e1 = st[(c0 + 1) * 64 + ((rr + c0 + 1) & 63)];
                float2 e2 = st[(c0 + 2) * 64 + ((rr + c0 + 2) & 63)];
                float2 e3 = st[(c0 + 3) * 64 + ((rr + c0 + 3) & 63)];
                v4f vl = { e0.x, e1.x, e2.x, e3.x };
                v4f vu = { e0.y, e1.y, e2.y, e3.y };
                const size_t off = (size_t)rr * NCOLS + (C + c0);
                __builtin_nontemporal_store(vl, (v4f*)(outl + off));
                __builtin_nontemporal_store(vu, (v4f*)(outu + off));
            }
        }
        // WAR on st across chunks ordered by the per-wave in-order DS pipe.
    }
}

extern "C" void kernel_launch(void* const* d_in, const int* in_sizes, int n_in,
                              void* d_out, int out_size, void* d_ws, size_t ws_size,
                              hipStream_t stream) {
    const float* xl = (const float*)d_in[0];
    const float* xu = (const float*)d_in[1];
    float* out = (float*)d_out;
    const int batch = in_sizes[0] / 16;              // 65536
    const int grid  = (batch / ROWS) * 2;            // 1024 groups x 2 col-halves
    minint_kernel<<<grid, BLOCK, 0, stream>>>(xl, xu, out, batch);
}

// Round 8
// 381.593 us; speedup vs baseline: 1.5317x; 1.5317x over previous
//
#include <hip/hip_runtime.h>
#include <cstdint>

#define NCOLS  696     // 16 + 120 + 560 subsets of size <= 3, bitmask order
#define NGROUP 174     // NCOLS / 4
#define NREC   136     // 16 singles + 120 pairs
#define WPB    4       // waves per block; wave = one row
#define BLOCK  256

typedef float v4f __attribute__((ext_vector_type(4)));

// Record id: single a -> a ; pair (a<b) -> 16 + b*(b-1)/2 + a.
constexpr int pr(int a, int b) { return 16 + b * (b - 1) / 2 + a; }

// Per-record source operands (lo | hi<<8): rec[r] = selpair(v[hi], v[lo]).
//  single a: (a,a) -> selpair(I_a, I_a) = I_a.
//  pair (a<b): selpair(L=I_b, R=I_a) = reference pairres(a,b).
struct alignas(8) RecSrc { uint16_t d[NREC]; };
constexpr RecSrc make_recs() {
    RecSrc t{};
    for (int a = 0; a < 16; ++a) t.d[a] = (uint16_t)(a | (a << 8));
    int p = 16;
    for (int b = 1; b < 16; ++b)
        for (int a = 0; a < b; ++a)
            t.d[p++] = (uint16_t)(a | (b << 8));
    return t;
}

// Per-column descriptor (Lrec | Rrec<<8): out = selpair(rec[Lrec], rec[Rrec]).
//  single {h}: L=R=h ; pair {j,h}: L=R=pr(j,h) ;
//  triple {i,j,h}: L=pr(j,h) (=combo[1:]), R=pr(i,j) (=combo[:-1]).
// Emission order = bitmask order. Validated absmax=0 (rounds 4-7 family).
struct alignas(8) ColTbl { uint16_t d[NCOLS]; };
constexpr ColTbl make_cols() {
    ColTbl t{};
    int p = 0;
    for (int h = 0; h < 16; ++h) {
        t.d[p++] = (uint16_t)(h | (h << 8));
        for (int j = 0; j < h; ++j) {
            int pjh = pr(j, h);
            t.d[p++] = (uint16_t)(pjh | (pjh << 8));
            for (int i = 0; i < j; ++i)
                t.d[p++] = (uint16_t)(pr(j, h) | (pr(i, j) << 8));
        }
    }
    return t;
}

__constant__ RecSrc g_recs = make_recs();
__constant__ ColTbl g_cols = make_cols();

// Tie-exact select. cur comparison uses the sum proxy: RN(0.5l+0.5u) =
// 0.5*RN(l+u) exactly, so ==/> match the NumPy fp32 reference bit-for-bit.
__device__ __forceinline__ float2 selpair(float2 L, float2 R) {
    float curL = __fadd_rn(L.x, L.y);
    float curR = __fadd_rn(R.x, R.y);
    float bL = __fadd_rn(__fmul_rn(0.2f, L.x), __fmul_rn(0.8f, L.y));
    float bR = __fadd_rn(__fmul_rn(0.2f, R.x), __fmul_rn(0.8f, R.y));
    bool choose_right = (curL == curR) ? (bL > bR) : (curL > curR);
    return choose_right ? R : L;
}

// Barrier-free round-4 structure: wave = row, 16384 blocks x 4 waves for
// latency-hiding oversubscription; 3 column-groups software-pipelined so
// gathers for group k+1 are in flight while group k computes/stores.
__global__ __launch_bounds__(BLOCK, 6) void minint_kernel(
    const float* __restrict__ xl, const float* __restrict__ xu,
    float* __restrict__ out, int batch)
{
    __shared__ float2 vals[WPB][16];
    __shared__ float2 recs[WPB][NREC];
    const int t    = threadIdx.x;
    const int w    = t >> 6;
    const int lane = t & 63;
    const int row  = blockIdx.x * WPB + w;

    float2* v   = vals[w];
    float2* rec = recs[w];

    // Self-load this wave's row: lanes 0..15 -> xl line, 16..31 -> xu line.
    // Same-wave LDS produce->consume: in-order DS pipe, no barrier needed
    // (validated round 5, absmax=0).
    if (lane < 32) {
        const float* src = (lane < 16) ? (xl + (size_t)row * 16 + lane)
                                       : (xu + (size_t)row * 16 + (lane - 16));
        ((float*)v)[(lane & 15) * 2 + (lane >> 4)] = *src;
    }

    // Build the 136 single/pair records (NREC = 64 + 64 + 8).
    {
        uint32_t s0 = g_recs.d[lane];
        uint32_t s1 = g_recs.d[64 + lane];
        float2 r0 = selpair(v[(s0 >> 8) & 15u], v[s0 & 15u]);
        float2 r1 = selpair(v[(s1 >> 8) & 15u], v[s1 & 15u]);
        rec[lane]      = r0;
        rec[64 + lane] = r1;
        if (lane < NREC - 128) {
            uint32_t s2 = g_recs.d[128 + lane];
            rec[128 + lane] = selpair(v[(s2 >> 8) & 15u], v[s2 & 15u]);
        }
    }

    float* outl = out + (size_t)row * NCOLS;
    float* outu = out + (size_t)batch * NCOLS + (size_t)row * NCOLS;
    const ushort4* cols = (const ushort4*)g_cols.d;

    // Column groups: g0 = lane, g1 = lane+64, g2 = lane+128 (lanes < 46).
    const bool has2 = lane < (NGROUP - 128);
    ushort4 d0 = cols[lane];
    ushort4 d1 = cols[64 + lane];
    ushort4 d2 = cols[has2 ? (128 + lane) : lane];   // safe dummy for inactive

    // ---- issue group-0 gathers (8 x ds_read_b64) ----
    float2 L00 = rec[d0.x & 255u], R00 = rec[d0.x >> 8];
    float2 L01 = rec[d0.y & 255u], R01 = rec[d0.y >> 8];
    float2 L02 = rec[d0.z & 255u], R02 = rec[d0.z >> 8];
    float2 L03 = rec[d0.w & 255u], R03 = rec[d0.w >> 8];
    // ---- issue group-1 gathers ----
    float2 L10 = rec[d1.x & 255u], R10 = rec[d1.x >> 8];
    float2 L11 = rec[d1.y & 255u], R11 = rec[d1.y >> 8];
    float2 L12 = rec[d1.z & 255u], R12 = rec[d1.z >> 8];
    float2 L13 = rec[d1.w & 255u], R13 = rec[d1.w >> 8];

    // ---- compute + store group 0 (group-1 gathers still in flight) ----
    {
        float2 c0 = selpair(L00, R00);
        float2 c1 = selpair(L01, R01);
        float2 c2 = selpair(L02, R02);
        float2 c3 = selpair(L03, R03);
        v4f rl = { c0.x, c1.x, c2.x, c3.x };
        v4f ru = { c0.y, c1.y, c2.y, c3.y };
        __builtin_nontemporal_store(rl, (v4f*)(outl + 4 * lane));
        __builtin_nontemporal_store(ru, (v4f*)(outu + 4 * lane));
    }

    // ---- issue group-2 gathers ----
    float2 L20 = rec[d2.x & 255u], R20 = rec[d2.x >> 8];
    float2 L21 = rec[d2.y & 255u], R21 = rec[d2.y >> 8];
    float2 L22 = rec[d2.z & 255u], R22 = rec[d2.z >> 8];
    float2 L23 = rec[d2.w & 255u], R23 = rec[d2.w >> 8];

    // ---- compute + store group 1 ----
    {
        float2 c0 = selpair(L10, R10);
        float2 c1 = selpair(L11, R11);
        float2 c2 = selpair(L12, R12);
        float2 c3 = selpair(L13, R13);
        v4f rl = { c0.x, c1.x, c2.x, c3.x };
        v4f ru = { c0.y, c1.y, c2.y, c3.y };
        __builtin_nontemporal_store(rl, (v4f*)(outl + 4 * (64 + lane)));
        __builtin_nontemporal_store(ru, (v4f*)(outu + 4 * (64 + lane)));
    }

    // ---- compute + store group 2 (lanes 0..45) ----
    if (has2) {
        float2 c0 = selpair(L20, R20);
        float2 c1 = selpair(L21, R21);
        float2 c2 = selpair(L22, R22);
        float2 c3 = selpair(L23, R23);
        v4f rl = { c0.x, c1.x, c2.x, c3.x };
        v4f ru = { c0.y, c1.y, c2.y, c3.y };
        __builtin_nontemporal_store(rl, (v4f*)(outl + 4 * (128 + lane)));
        __builtin_nontemporal_store(ru, (v4f*)(outu + 4 * (128 + lane)));
    }
}

extern "C" void kernel_launch(void* const* d_in, const int* in_sizes, int n_in,
                              void* d_out, int out_size, void* d_ws, size_t ws_size,
                              hipStream_t stream) {
    const float* xl = (const float*)d_in[0];
    const float* xu = (const float*)d_in[1];
    float* out = (float*)d_out;
    const int batch = in_sizes[0] / 16;          // 65536
    const int grid  = batch / WPB;               // 16384 blocks x 4 waves
    minint_kernel<<<grid, BLOCK, 0, stream>>>(xl, xu, out, batch);
}

// Round 9
// 377.489 us; speedup vs baseline: 1.5484x; 1.0109x over previous
//
#include <hip/hip_runtime.h>
#include <cstdint>

#define NCOLS  696     // 16 + 120 + 560 subsets of size <= 3, bitmask order
#define NGROUP 174     // NCOLS / 4
#define NREC   136     // 16 singles + 120 pairs
#define WPB    4       // waves per block; wave = one row
#define BLOCK  256

typedef float v4f __attribute__((ext_vector_type(4)));

// Record id: single a -> a ; pair (a<b) -> 16 + b*(b-1)/2 + a.
constexpr int pr(int a, int b) { return 16 + b * (b - 1) / 2 + a; }

// Per-record source operands (lo | hi<<8): rec[r] = selpair(v[hi], v[lo]).
struct alignas(8) RecSrc { uint16_t d[NREC]; };
constexpr RecSrc make_recs() {
    RecSrc t{};
    for (int a = 0; a < 16; ++a) t.d[a] = (uint16_t)(a | (a << 8));
    int p = 16;
    for (int b = 1; b < 16; ++b)
        for (int a = 0; a < b; ++a)
            t.d[p++] = (uint16_t)(a | (b << 8));
    return t;
}

// Per-column descriptor (Lrec | Rrec<<8): out = selpair(rec[Lrec], rec[Rrec]).
//  single {h}: L=R=h ; pair {j,h}: L=R=pr(j,h) ;
//  triple {i,j,h}: L=pr(j,h) (=combo[1:]), R=pr(i,j) (=combo[:-1]).
// Emission order = bitmask order. Validated absmax=0 (rounds 4-8).
struct alignas(8) ColTbl { uint16_t d[NCOLS]; };
constexpr ColTbl make_cols() {
    ColTbl t{};
    int p = 0;
    for (int h = 0; h < 16; ++h) {
        t.d[p++] = (uint16_t)(h | (h << 8));
        for (int j = 0; j < h; ++j) {
            int pjh = pr(j, h);
            t.d[p++] = (uint16_t)(pjh | (pjh << 8));
            for (int i = 0; i < j; ++i)
                t.d[p++] = (uint16_t)(pr(j, h) | (pr(i, j) << 8));
        }
    }
    return t;
}

__constant__ RecSrc g_recs = make_recs();
__constant__ ColTbl g_cols = make_cols();

// Tie-exact select. cur comparison uses the sum proxy: RN(0.5l+0.5u) =
// 0.5*RN(l+u) exactly, so ==/> match the NumPy fp32 reference bit-for-bit.
__device__ __forceinline__ float2 selpair(float2 L, float2 R) {
    float curL = __fadd_rn(L.x, L.y);
    float curR = __fadd_rn(R.x, R.y);
    float bL = __fadd_rn(__fmul_rn(0.2f, L.x), __fmul_rn(0.8f, L.y));
    float bR = __fadd_rn(__fmul_rn(0.2f, R.x), __fmul_rn(0.8f, R.y));
    bool choose_right = (curL == curR) ? (bL > bR) : (curL > curR);
    return choose_right ? R : L;
}

__device__ __forceinline__ float2 col_compute(const float2* __restrict__ rec,
                                              uint32_t d) {
    float2 L = rec[d & 255u];
    float2 R = rec[(d >> 8) & 255u];
    return selpair(L, R);
}

// R4/R8 compute structure (wave = row, barrier-free), with:
//  - plain stores (L2 write-combining merges the straddled row-boundary
//    lines; rows are 2784 B, not 128 B-aligned)
//  - XCD-contiguous row mapping: dispatch round-robins blocks over 8 XCDs,
//    so remap bid -> grp = (bid&7)*2048 + (bid>>3): each XCD-residue class
//    owns a contiguous 8192-row (22.8 MB) output range; straddled lines are
//    produced and merged within a single XCD's L2.
__global__ __launch_bounds__(BLOCK) void minint_kernel(
    const float* __restrict__ xl, const float* __restrict__ xu,
    float* __restrict__ out, int batch)
{
    __shared__ float2 vals[WPB][16];
    __shared__ float2 recs[WPB][NREC];
    const int t    = threadIdx.x;
    const int w    = t >> 6;
    const int lane = t & 63;
    const int bid  = blockIdx.x;
    const int grp  = ((bid & 7) << 11) | (bid >> 3);   // XCD-contiguous rows
    const int row  = grp * WPB + w;

    float2* v   = vals[w];
    float2* rec = recs[w];

    // Self-load this wave's row: lanes 0..15 -> xl line, 16..31 -> xu line.
    // Same-wave LDS produce->consume: in-order DS pipe, no barrier (R5/R8).
    if (lane < 32) {
        const float* src = (lane < 16) ? (xl + (size_t)row * 16 + lane)
                                       : (xu + (size_t)row * 16 + (lane - 16));
        ((float*)v)[(lane & 15) * 2 + (lane >> 4)] = *src;
    }

    // Build the 136 single/pair records (NREC = 64 + 64 + 8).
    {
        uint32_t s0 = g_recs.d[lane];
        uint32_t s1 = g_recs.d[64 + lane];
        float2 r0 = selpair(v[(s0 >> 8) & 15u], v[s0 & 15u]);
        float2 r1 = selpair(v[(s1 >> 8) & 15u], v[s1 & 15u]);
        rec[lane]      = r0;
        rec[64 + lane] = r1;
        if (lane < NREC - 128) {
            uint32_t s2 = g_recs.d[128 + lane];
            rec[128 + lane] = selpair(v[(s2 >> 8) & 15u], v[s2 & 15u]);
        }
    }

    float* outl = out + (size_t)row * NCOLS;
    float* outu = out + (size_t)batch * NCOLS + (size_t)row * NCOLS;
    const ushort4* cols = (const ushort4*)g_cols.d;

    // 174 quads: lane handles quads {lane, lane+64, lane+128<174}; each
    // store = 16B/lane, 64 ascending lanes = 1KB contiguous per instruction.
    #pragma unroll
    for (int k = 0; k < 3; ++k) {
        int g = lane + 64 * k;
        if (g < NGROUP) {
            ushort4 d4 = cols[g];
            float2 c0 = col_compute(rec, d4.x);
            float2 c1 = col_compute(rec, d4.y);
            float2 c2 = col_compute(rec, d4.z);
            float2 c3 = col_compute(rec, d4.w);
            v4f rl = { c0.x, c1.x, c2.x, c3.x };
            v4f ru = { c0.y, c1.y, c2.y, c3.y };
            *(v4f*)(outl + 4 * g) = rl;   // plain stores: let L2 merge
            *(v4f*)(outu + 4 * g) = ru;
        }
    }
}

extern "C" void kernel_launch(void* const* d_in, const int* in_sizes, int n_in,
                              void* d_out, int out_size, void* d_ws, size_t ws_size,
                              hipStream_t stream) {
    const float* xl = (const float*)d_in[0];
    const float* xu = (const float*)d_in[1];
    float* out = (float*)d_out;
    const int batch = in_sizes[0] / 16;          // 65536
    const int grid  = batch / WPB;               // 16384 blocks x 4 waves
    minint_kernel<<<grid, BLOCK, 0, stream>>>(xl, xu, out, batch);
}